// Round 1
// baseline (146.278 us; speedup 1.0000x reference)
//
#include <hip/hip_runtime.h>
#include <hip/hip_bf16.h>
#include <stdint.h>

#define DEVI __device__ __forceinline__

typedef __attribute__((ext_vector_type(8))) short short8;
typedef __attribute__((ext_vector_type(4))) float floatx4;

DEVI ushort f2bf(float f) {
  union { float f; uint32_t u; } v; v.f = f;
  uint32_t u = v.u;
  uint32_t r = (u + 0x7FFFu + ((u >> 16) & 1u)) >> 16;
  return (ushort)r;
}
DEVI float bf2f(ushort h) {
  union { uint32_t u; float f; } v; v.u = ((uint32_t)h) << 16;
  return v.f;
}
DEVI void gld_lds16(const void* g, void* l) {
  __builtin_amdgcn_global_load_lds(
      (const __attribute__((address_space(1))) unsigned int*)g,
      (__attribute__((address_space(3))) unsigned int*)l, 16, 0, 0);
}

// ---------------- cast fp32 -> bf16 ----------------
__global__ __launch_bounds__(256, 4) void cast_f32_bf16(
    const float* __restrict__ in, ushort* __restrict__ out, int n) {
  int i = (blockIdx.x * 256 + threadIdx.x) * 4;
  int stride = gridDim.x * 256 * 4;
  for (; i < n; i += stride) {
    float4 v = *(const float4*)(in + i);
    ushort4 o;
    o.x = f2bf(v.x); o.y = f2bf(v.y); o.z = f2bf(v.z); o.w = f2bf(v.w);
    *(ushort4*)(out + i) = o;
  }
}

// ---------------- RoPE cos/sin table ----------------
__global__ __launch_bounds__(256, 4) void rope_table(float2* __restrict__ tab) {
  int id = blockIdx.x * 256 + threadIdx.x;  // 1024*32
  int j = id & 31, n = id >> 5;
  float inv = powf(10000.0f, -(float)(2 * j) / 64.0f);
  float fr = (float)n * inv;
  tab[id] = make_float2(cosf(fr), sinf(fr));
}

// ---------------- GEMM: C[M][N] = A[M][K] * B[N][K]^T + bias ----------------
// A row-major (M x K) bf16, B row-major (N x K) bf16 (i.e. B^T layout).
// 128x128 tile, BK=32, 4 waves (2x2), 16x16x32 bf16 MFMA. m97 structure.
template <int NSTRIDE, bool OUTBF16>
__global__ __launch_bounds__(256, 2) void gemm_bt(
    const ushort* __restrict__ A, const ushort* __restrict__ Bm,
    const float* __restrict__ bias, void* __restrict__ Cout, int K) {
  __shared__ ushort As[128 * 32];
  __shared__ ushort Bs[128 * 32];
  const int tid = threadIdx.x;
  const int w = tid >> 6, lane = tid & 63;
  const int m0 = blockIdx.y * 128, n0 = blockIdx.x * 128;
  const int wm = (w >> 1) * 64, wn = (w & 1) * 64;
  const int lrow = lane & 15, lk = (lane >> 4) * 8;

  const ushort* agp = A + (size_t)(m0 + w * 32 + (lane >> 2)) * K + (lane & 3) * 8;
  const ushort* bgp = Bm + (size_t)(n0 + w * 32 + (lane >> 2)) * K + (lane & 3) * 8;
  ushort* asl = As + (w * 32) * 32 + lane * 8;
  ushort* bsl = Bs + (w * 32) * 32 + lane * 8;

  floatx4 acc[4][4] = {};

  for (int k0 = 0; k0 < K; k0 += 32) {
    __syncthreads();
    gld_lds16(agp, asl);
    gld_lds16(agp + 16 * K, asl + 16 * 32);
    gld_lds16(bgp, bsl);
    gld_lds16(bgp + 16 * K, bsl + 16 * 32);
    agp += 32; bgp += 32;
    __syncthreads();
    short8 af[4], bf[4];
#pragma unroll
    for (int t = 0; t < 4; ++t) {
      af[t] = *(const short8*)(As + (wm + t * 16 + lrow) * 32 + lk);
      bf[t] = *(const short8*)(Bs + (wn + t * 16 + lrow) * 32 + lk);
    }
#pragma unroll
    for (int i = 0; i < 4; ++i)
#pragma unroll
      for (int j = 0; j < 4; ++j)
        acc[i][j] = __builtin_amdgcn_mfma_f32_16x16x32_bf16(af[i], bf[j], acc[i][j], 0, 0, 0);
  }

  // epilogue: C/D layout col = lane&15, row = (lane>>4)*4 + reg  [m89-verified]
#pragma unroll
  for (int i = 0; i < 4; ++i) {
    int mrow = m0 + wm + i * 16 + (lane >> 4) * 4;
#pragma unroll
    for (int j = 0; j < 4; ++j) {
      int ncol = n0 + wn + j * 16 + (lane & 15);
      float bv = bias[ncol];
#pragma unroll
      for (int r = 0; r < 4; ++r) {
        float v = acc[i][j][r] + bv;
        if (OUTBF16)
          ((ushort*)Cout)[(size_t)(mrow + r) * NSTRIDE + ncol] = f2bf(v);
        else
          ((float*)Cout)[(size_t)(mrow + r) * NSTRIDE + ncol] = v;
      }
    }
  }
}

// ---------------- RoPE + scatter q,k -> (b,h,n,d) ----------------
__global__ __launch_bounds__(256, 4) void rope_qk(
    const ushort* __restrict__ qkv, const float2* __restrict__ tab,
    ushort* __restrict__ Q, ushort* __restrict__ Kb) {
  int id = blockIdx.x * 256 + threadIdx.x;  // 4096*16*32
  int j = id & 31;
  int h = (id >> 5) & 15;
  int m = id >> 9;  // 0..4095
  int b = m >> 10, n = m & 1023;
  const ushort* row = qkv + (size_t)m * 3072;
  int idx = h * 64 + 2 * j;
  uint32_t qp = *(const uint32_t*)(row + idx);
  uint32_t kp = *(const uint32_t*)(row + 1024 + idx);
  float2 cs = tab[n * 32 + j];
  float q0 = bf2f((ushort)qp), q1 = bf2f((ushort)(qp >> 16));
  float k0 = bf2f((ushort)kp), k1 = bf2f((ushort)(kp >> 16));
  const float sc = 1.0f / 64.0f;  // scale^2 folded into Q
  float q0r = (q0 * cs.x - q1 * cs.y) * sc;
  float q1r = (q1 * cs.x + q0 * cs.y) * sc;
  float k0r = k0 * cs.x - k1 * cs.y;
  float k1r = k1 * cs.x + k0 * cs.y;
  size_t o = ((size_t)(b * 16 + h) * 1024 + n) * 64 + 2 * j;
  *(uint32_t*)(Q + o) = (uint32_t)f2bf(q0r) | ((uint32_t)f2bf(q1r) << 16);
  *(uint32_t*)(Kb + o) = (uint32_t)f2bf(k0r) | ((uint32_t)f2bf(k1r) << 16);
}

// ---------------- V transpose -> Vt (b,h,d,n) ----------------
__global__ __launch_bounds__(256, 4) void v_trans(
    const ushort* __restrict__ qkv, ushort* __restrict__ Vt) {
  __shared__ ushort t[64][72];
  int bh = blockIdx.y, ntile = blockIdx.x;
  int b = bh >> 4, h = bh & 15;
  int n0 = ntile * 64;
  int tid = threadIdx.x;
  int r = tid >> 2, cc = (tid & 3) * 16;
  const ushort* src = qkv + (size_t)(b * 1024 + n0 + r) * 3072 + 2048 + h * 64 + cc;
  *(short8*)(&t[r][cc]) = *(const short8*)(src);
  *(short8*)(&t[r][cc + 8]) = *(const short8*)(src + 8);
  __syncthreads();
  int d = tid >> 2;
  ushort outv[16];
#pragma unroll
  for (int i = 0; i < 16; ++i) outv[i] = t[cc + i][d];
  ushort* dst = Vt + (size_t)bh * 65536 + (size_t)d * 1024 + n0 + cc;
  *(short8*)(dst) = *(const short8*)(outv);
  *(short8*)(dst + 8) = *(const short8*)(outv + 8);
}

// ---------------- Flash attention ----------------
// Q tile 128 rows/block, 4 waves (32 rows each), KV tiles of 64.
// K_lds/Vt_lds/P_lds all XOR-swizzled: byte ^= ((row&7)<<4)  [G4]
__global__ __launch_bounds__(256, 2) void attn(
    const ushort* __restrict__ Q, const ushort* __restrict__ Kc,
    const ushort* __restrict__ Vt, ushort* __restrict__ AO) {
  __shared__ ushort Ks[64 * 64];
  __shared__ ushort Vs[64 * 64];
  __shared__ ushort Ps[128 * 64];
  int bh = blockIdx.y;
  int b = bh >> 4, h = bh & 15;
  int q0 = blockIdx.x * 128;
  int tid = threadIdx.x, w = tid >> 6, lane = tid & 63;
  int lrow = lane & 15, lk16 = (lane >> 4);
  const ushort* Qbh = Q + (size_t)bh * 65536;
  const char* Kbh = (const char*)(Kc + (size_t)bh * 65536);
  const char* Vbh = (const char*)(Vt + (size_t)bh * 65536);

  short8 qf[2][2];
#pragma unroll
  for (int mt = 0; mt < 2; ++mt)
#pragma unroll
    for (int ks = 0; ks < 2; ++ks)
      qf[mt][ks] = *(const short8*)(Qbh + (size_t)(q0 + w * 32 + mt * 16 + lrow) * 64 + ks * 32 + lk16 * 8);

  floatx4 oacc[2][4] = {};
  float mrun[2][4], lrun[2][4];
#pragma unroll
  for (int mt = 0; mt < 2; ++mt)
#pragma unroll
    for (int r = 0; r < 4; ++r) { mrun[mt][r] = -1e30f; lrun[mt][r] = 0.f; }

  const int dst0 = w * 2048 + lane * 16;
  const int dst1 = dst0 + 1024;

  for (int kt = 0; kt < 16; ++kt) {
    __syncthreads();
    {
      int d0 = dst0, r0 = d0 >> 7, s0 = d0 ^ ((r0 & 7) << 4);
      int d1 = dst1, r1 = d1 >> 7, s1 = d1 ^ ((r1 & 7) << 4);
      gld_lds16(Kbh + kt * 8192 + s0, (char*)Ks + d0);
      gld_lds16(Kbh + kt * 8192 + s1, (char*)Ks + d1);
      gld_lds16(Vbh + r0 * 2048 + kt * 128 + (s0 & 127), (char*)Vs + d0);
      gld_lds16(Vbh + r1 * 2048 + kt * 128 + (s1 & 127), (char*)Vs + d1);
    }
    __syncthreads();

    // S = Q K^T   (scale already folded into Q)
    floatx4 sacc[2][4] = {};
#pragma unroll
    for (int ks = 0; ks < 2; ++ks) {
      short8 kf[4];
#pragma unroll
      for (int nt = 0; nt < 4; ++nt) {
        int row = nt * 16 + lrow;
        int lin = row * 128 + ks * 64 + lk16 * 16;
        kf[nt] = *(const short8*)((const char*)Ks + (lin ^ ((row & 7) << 4)));
      }
#pragma unroll
      for (int mt = 0; mt < 2; ++mt)
#pragma unroll
        for (int nt = 0; nt < 4; ++nt)
          sacc[mt][nt] = __builtin_amdgcn_mfma_f32_16x16x32_bf16(qf[mt][ks], kf[nt], sacc[mt][nt], 0, 0, 0);
    }

    // online softmax (rows live in 16-lane groups; reg r -> row (lane>>4)*4+r)
#pragma unroll
    for (int mt = 0; mt < 2; ++mt) {
#pragma unroll
      for (int r = 0; r < 4; ++r) {
        float mx = fmaxf(fmaxf(sacc[mt][0][r], sacc[mt][1][r]),
                         fmaxf(sacc[mt][2][r], sacc[mt][3][r]));
#pragma unroll
        for (int off = 1; off < 16; off <<= 1) mx = fmaxf(mx, __shfl_xor(mx, off));
        float mnew = fmaxf(mrun[mt][r], mx);
        float corr = __expf(mrun[mt][r] - mnew);
        float rs = 0.f;
#pragma unroll
        for (int nt = 0; nt < 4; ++nt) {
          float p = __expf(sacc[mt][nt][r] - mnew);
          sacc[mt][nt][r] = p;
          rs += p;
        }
#pragma unroll
        for (int off = 1; off < 16; off <<= 1) rs += __shfl_xor(rs, off);
        lrun[mt][r] = lrun[mt][r] * corr + rs;
        mrun[mt][r] = mnew;
#pragma unroll
        for (int dt = 0; dt < 4; ++dt) oacc[mt][dt][r] *= corr;
      }
#pragma unroll
      for (int nt = 0; nt < 4; ++nt) {
#pragma unroll
        for (int r = 0; r < 4; ++r) {
          int m = w * 32 + mt * 16 + lk16 * 4 + r;
          int n = nt * 16 + lrow;
          int lin = m * 128 + n * 2;
          *(ushort*)((char*)Ps + (lin ^ ((m & 7) << 4))) = f2bf(sacc[mt][nt][r]);
        }
      }
    }

    // O += P V   (wave reads only its own P rows; lgkmcnt dep handled by compiler)
#pragma unroll
    for (int ks = 0; ks < 2; ++ks) {
      short8 pf[2], vf[4];
#pragma unroll
      for (int mt = 0; mt < 2; ++mt) {
        int m = w * 32 + mt * 16 + lrow;
        int lin = m * 128 + ks * 64 + lk16 * 16;
        pf[mt] = *(const short8*)((const char*)Ps + (lin ^ ((m & 7) << 4)));
      }
#pragma unroll
      for (int dt = 0; dt < 4; ++dt) {
        int row = dt * 16 + lrow;
        int lin = row * 128 + ks * 64 + lk16 * 16;
        vf[dt] = *(const short8*)((const char*)Vs + (lin ^ ((row & 7) << 4)));
      }
#pragma unroll
      for (int mt = 0; mt < 2; ++mt)
#pragma unroll
        for (int dt = 0; dt < 4; ++dt)
          oacc[mt][dt] = __builtin_amdgcn_mfma_f32_16x16x32_bf16(pf[mt], vf[dt], oacc[mt][dt], 0, 0, 0);
    }
  }

  // epilogue: AO[(b*1024 + n)][h*64 + d] bf16
#pragma unroll
  for (int mt = 0; mt < 2; ++mt) {
#pragma unroll
    for (int r = 0; r < 4; ++r) {
      int mloc = w * 32 + mt * 16 + lk16 * 4 + r;
      int nseq = q0 + mloc;
      float inv = 1.0f / lrun[mt][r];
#pragma unroll
      for (int dt = 0; dt < 4; ++dt) {
        int d = dt * 16 + lrow;
        AO[(size_t)(b * 1024 + nseq) * 1024 + h * 64 + d] = f2bf(oacc[mt][dt][r] * inv);
      }
    }
  }
}

extern "C" void kernel_launch(void* const* d_in, const int* in_sizes, int n_in,
                              void* d_out, int out_size, void* d_ws, size_t ws_size,
                              hipStream_t stream) {
  const float* x = (const float*)d_in[0];
  const float* qkv_w = (const float*)d_in[1];
  const float* qkv_b = (const float*)d_in[2];
  const float* proj_w = (const float*)d_in[3];
  const float* proj_b = (const float*)d_in[4];
  float* out = (float*)d_out;

  char* ws = (char*)d_ws;
  size_t off = 0;
  auto alloc = [&](size_t bytes) -> void* {
    void* p = ws + off;
    off += (bytes + 255) & ~(size_t)255;
    return p;
  };
  ushort* xb = (ushort*)alloc(4096ull * 1024 * 2);
  ushort* wqkvb = (ushort*)alloc(3072ull * 1024 * 2);
  ushort* wprojb = (ushort*)alloc(1024ull * 1024 * 2);
  ushort* qkv = (ushort*)alloc(4096ull * 3072 * 2);
  ushort* Qb = (ushort*)alloc(64ull * 1024 * 64 * 2);
  ushort* Kb = (ushort*)alloc(64ull * 1024 * 64 * 2);
  ushort* Vt = (ushort*)alloc(64ull * 1024 * 64 * 2);
  ushort* AO = (ushort*)alloc(4096ull * 1024 * 2);
  float2* tab = (float2*)alloc(1024ull * 32 * sizeof(float2));

  cast_f32_bf16<<<2048, 256, 0, stream>>>(x, xb, 4096 * 1024);
  cast_f32_bf16<<<1536, 256, 0, stream>>>(qkv_w, wqkvb, 3072 * 1024);
  cast_f32_bf16<<<512, 256, 0, stream>>>(proj_w, wprojb, 1024 * 1024);
  rope_table<<<128, 256, 0, stream>>>(tab);

  dim3 g1(24, 32);
  gemm_bt<3072, true><<<g1, 256, 0, stream>>>(xb, wqkvb, qkv_b, qkv, 1024);

  rope_qk<<<8192, 256, 0, stream>>>(qkv, tab, Qb, Kb);
  dim3 gv(16, 64);
  v_trans<<<gv, 256, 0, stream>>>(qkv, Vt);

  dim3 ga(8, 64);
  attn<<<ga, 256, 0, stream>>>(Qb, Kb, Vt, AO);

  dim3 g2(8, 32);
  gemm_bt<1024, false><<<g2, 256, 0, stream>>>(AO, wprojb, proj_b, out, 1024);
}

// Round 2
// 123.491 us; speedup vs baseline: 1.1845x; 1.1845x over previous
//
#include <hip/hip_runtime.h>
#include <hip/hip_bf16.h>
#include <stdint.h>

#define DEVI __device__ __forceinline__

typedef __attribute__((ext_vector_type(8))) short short8;
typedef __attribute__((ext_vector_type(4))) short short4v;
typedef __attribute__((ext_vector_type(4))) float floatx4;

DEVI ushort f2bf(float f) {
  union { float f; uint32_t u; } v; v.f = f;
  uint32_t u = v.u;
  uint32_t r = (u + 0x7FFFu + ((u >> 16) & 1u)) >> 16;
  return (ushort)r;
}
// fast round-to-nearest (no RNE tie handling) — fine for P in (0,1]
DEVI ushort f2bf_fast(float f) {
  union { float f; uint32_t u; } v; v.f = f;
  return (ushort)((v.u + 0x8000u) >> 16);
}
DEVI float bf2f(ushort h) {
  union { uint32_t u; float f; } v; v.u = ((uint32_t)h) << 16;
  return v.f;
}
DEVI void gld_lds16(const void* g, void* l) {
  __builtin_amdgcn_global_load_lds(
      (const __attribute__((address_space(1))) unsigned int*)g,
      (__attribute__((address_space(3))) unsigned int*)l, 16, 0, 0);
}

// ---------------- cast fp32 -> bf16 ----------------
__global__ __launch_bounds__(256, 4) void cast_f32_bf16(
    const float* __restrict__ in, ushort* __restrict__ out, int n) {
  int i = (blockIdx.x * 256 + threadIdx.x) * 4;
  int stride = gridDim.x * 256 * 4;
  for (; i < n; i += stride) {
    float4 v = *(const float4*)(in + i);
    ushort4 o;
    o.x = f2bf(v.x); o.y = f2bf(v.y); o.z = f2bf(v.z); o.w = f2bf(v.w);
    *(ushort4*)(out + i) = o;
  }
}

// ---------------- RoPE cos/sin table ----------------
__global__ __launch_bounds__(256, 4) void rope_table(float2* __restrict__ tab) {
  int id = blockIdx.x * 256 + threadIdx.x;  // 1024*32
  int j = id & 31, n = id >> 5;
  float inv = powf(10000.0f, -(float)(2 * j) / 64.0f);
  float fr = (float)n * inv;
  tab[id] = make_float2(cosf(fr), sinf(fr));
}

// ---------------- GEMM: C[M][N] = A[M][K] * B[N][K]^T + bias ----------------
template <int NSTRIDE, bool OUTBF16>
__global__ __launch_bounds__(256, 2) void gemm_bt(
    const ushort* __restrict__ A, const ushort* __restrict__ Bm,
    const float* __restrict__ bias, void* __restrict__ Cout, int K) {
  __shared__ ushort As[128 * 32];
  __shared__ ushort Bs[128 * 32];
  const int tid = threadIdx.x;
  const int w = tid >> 6, lane = tid & 63;
  const int m0 = blockIdx.y * 128, n0 = blockIdx.x * 128;
  const int wm = (w >> 1) * 64, wn = (w & 1) * 64;
  const int lrow = lane & 15, lk = (lane >> 4) * 8;

  const ushort* agp = A + (size_t)(m0 + w * 32 + (lane >> 2)) * K + (lane & 3) * 8;
  const ushort* bgp = Bm + (size_t)(n0 + w * 32 + (lane >> 2)) * K + (lane & 3) * 8;
  ushort* asl = As + (w * 32) * 32 + lane * 8;
  ushort* bsl = Bs + (w * 32) * 32 + lane * 8;

  floatx4 acc[4][4] = {};

  for (int k0 = 0; k0 < K; k0 += 32) {
    __syncthreads();
    gld_lds16(agp, asl);
    gld_lds16(agp + 16 * K, asl + 16 * 32);
    gld_lds16(bgp, bsl);
    gld_lds16(bgp + 16 * K, bsl + 16 * 32);
    agp += 32; bgp += 32;
    __syncthreads();
    short8 af[4], bf[4];
#pragma unroll
    for (int t = 0; t < 4; ++t) {
      af[t] = *(const short8*)(As + (wm + t * 16 + lrow) * 32 + lk);
      bf[t] = *(const short8*)(Bs + (wn + t * 16 + lrow) * 32 + lk);
    }
#pragma unroll
    for (int i = 0; i < 4; ++i)
#pragma unroll
      for (int j = 0; j < 4; ++j)
        acc[i][j] = __builtin_amdgcn_mfma_f32_16x16x32_bf16(af[i], bf[j], acc[i][j], 0, 0, 0);
  }

#pragma unroll
  for (int i = 0; i < 4; ++i) {
    int mrow = m0 + wm + i * 16 + (lane >> 4) * 4;
#pragma unroll
    for (int j = 0; j < 4; ++j) {
      int ncol = n0 + wn + j * 16 + (lane & 15);
      float bv = bias[ncol];
#pragma unroll
      for (int r = 0; r < 4; ++r) {
        float v = acc[i][j][r] + bv;
        if (OUTBF16)
          ((ushort*)Cout)[(size_t)(mrow + r) * NSTRIDE + ncol] = f2bf(v);
        else
          ((float*)Cout)[(size_t)(mrow + r) * NSTRIDE + ncol] = v;
      }
    }
  }
}

// ---------------- RoPE + scatter q,k -> (b,h,n,d) ----------------
__global__ __launch_bounds__(256, 4) void rope_qk(
    const ushort* __restrict__ qkv, const float2* __restrict__ tab,
    ushort* __restrict__ Q, ushort* __restrict__ Kb) {
  int id = blockIdx.x * 256 + threadIdx.x;  // 4096*16*32
  int j = id & 31;
  int h = (id >> 5) & 15;
  int m = id >> 9;  // 0..4095
  int b = m >> 10, n = m & 1023;
  const ushort* row = qkv + (size_t)m * 3072;
  int idx = h * 64 + 2 * j;
  uint32_t qp = *(const uint32_t*)(row + idx);
  uint32_t kp = *(const uint32_t*)(row + 1024 + idx);
  float2 cs = tab[n * 32 + j];
  float q0 = bf2f((ushort)qp), q1 = bf2f((ushort)(qp >> 16));
  float k0 = bf2f((ushort)kp), k1 = bf2f((ushort)(kp >> 16));
  const float sc = 1.0f / 64.0f;  // scale^2 folded into Q
  float q0r = (q0 * cs.x - q1 * cs.y) * sc;
  float q1r = (q1 * cs.x + q0 * cs.y) * sc;
  float k0r = k0 * cs.x - k1 * cs.y;
  float k1r = k1 * cs.x + k0 * cs.y;
  size_t o = ((size_t)(b * 16 + h) * 1024 + n) * 64 + 2 * j;
  *(uint32_t*)(Q + o) = (uint32_t)f2bf(q0r) | ((uint32_t)f2bf(q1r) << 16);
  *(uint32_t*)(Kb + o) = (uint32_t)f2bf(k0r) | ((uint32_t)f2bf(k1r) << 16);
}

// ---------------- V transpose -> Vt (b,h,d,n) ----------------
__global__ __launch_bounds__(256, 4) void v_trans(
    const ushort* __restrict__ qkv, ushort* __restrict__ Vt) {
  __shared__ ushort t[64][72];
  int bh = blockIdx.y, ntile = blockIdx.x;
  int b = bh >> 4, h = bh & 15;
  int n0 = ntile * 64;
  int tid = threadIdx.x;
  int r = tid >> 2, cc = (tid & 3) * 16;
  const ushort* src = qkv + (size_t)(b * 1024 + n0 + r) * 3072 + 2048 + h * 64 + cc;
  *(short8*)(&t[r][cc]) = *(const short8*)(src);
  *(short8*)(&t[r][cc + 8]) = *(const short8*)(src + 8);
  __syncthreads();
  int d = tid >> 2;
  ushort outv[16];
#pragma unroll
  for (int i = 0; i < 16; ++i) outv[i] = t[cc + i][d];
  ushort* dst = Vt + (size_t)bh * 65536 + (size_t)d * 1024 + n0 + cc;
  *(short8*)(dst) = *(const short8*)(outv);
  *(short8*)(dst + 8) = *(const short8*)(outv + 8);
}

// ---------------- Flash attention v2 ----------------
// Swapped QK^T (S^T: q = lane&15), in-register softmax, P stays in registers,
// PV via programmable k-slot packing of 16x16x32 MFMA (zero cross-lane exchange).
// Q tile 64 rows/block (wave owns 16), KV tiles 64, grid 1024 = 4 blocks/CU.
// 1-D grid, bh = id&63 -> all q-tiles of a bh land on XCD bh%8 (L2-resident KV).
__global__ __launch_bounds__(256, 4) void attn(
    const ushort* __restrict__ Q, const ushort* __restrict__ Kc,
    const ushort* __restrict__ Vt, ushort* __restrict__ AO) {
  __shared__ ushort Ks[64 * 64];
  __shared__ ushort Vs[64 * 64];
  int id = blockIdx.x;
  int bh = id & 63, qi = id >> 6;
  int b = bh >> 4, h = bh & 15;
  int q0 = qi * 64;
  int tid = threadIdx.x, w = tid >> 6, lane = tid & 63;
  int l15 = lane & 15, g = lane >> 4;
  const ushort* Qbh = Q + (size_t)bh * 65536;
  const char* Kbh = (const char*)(Kc + (size_t)bh * 65536);
  const char* Vbh = (const char*)(Vt + (size_t)bh * 65536);

  // Q fragment (B-operand of swapped QK^T): wave owns q rows q0+w*16 .. +15
  short8 qf[2];
#pragma unroll
  for (int ks = 0; ks < 2; ++ks)
    qf[ks] = *(const short8*)(Qbh + (size_t)(q0 + w * 16 + l15) * 64 + ks * 32 + g * 8);

  floatx4 oacc[4] = {};
  float mrun = -1e30f, lrun = 0.f;

  const int dst0 = w * 2048 + lane * 16;
  const int dst1 = dst0 + 1024;

  for (int kt = 0; kt < 16; ++kt) {
    __syncthreads();
    {
      int d0 = dst0, r0 = d0 >> 7, s0 = d0 ^ ((r0 & 7) << 4);
      int d1 = dst1, r1 = d1 >> 7, s1 = d1 ^ ((r1 & 7) << 4);
      gld_lds16(Kbh + kt * 8192 + s0, (char*)Ks + d0);
      gld_lds16(Kbh + kt * 8192 + s1, (char*)Ks + d1);
      gld_lds16(Vbh + r0 * 2048 + kt * 128 + (s0 & 127), (char*)Vs + d0);
      gld_lds16(Vbh + r1 * 2048 + kt * 128 + (s1 & 127), (char*)Vs + d1);
    }
    __syncthreads();

    // S^T = mfma(K, Q): D[key_loc][q], key_loc = nt*16 + g*4 + r, q = l15
    floatx4 sacc[4] = {};
#pragma unroll
    for (int ks = 0; ks < 2; ++ks) {
      short8 kf[4];
#pragma unroll
      for (int nt = 0; nt < 4; ++nt) {
        int row = nt * 16 + l15;
        int lin = row * 128 + ks * 64 + g * 16;
        kf[nt] = *(const short8*)((const char*)Ks + (lin ^ ((row & 7) << 4)));
      }
#pragma unroll
      for (int nt = 0; nt < 4; ++nt)
        sacc[nt] = __builtin_amdgcn_mfma_f32_16x16x32_bf16(kf[nt], qf[ks], sacc[nt], 0, 0, 0);
    }

    // online softmax for q-column l15: 16 in-reg values + 2-shfl cross-group
    float mx = sacc[0][0];
#pragma unroll
    for (int nt = 0; nt < 4; ++nt)
#pragma unroll
      for (int r = 0; r < 4; ++r) mx = fmaxf(mx, sacc[nt][r]);
    mx = fmaxf(mx, __shfl_xor(mx, 16));
    mx = fmaxf(mx, __shfl_xor(mx, 32));
    float mnew = fmaxf(mrun, mx);
    float corr = __expf(mrun - mnew);
    float rs = 0.f;
#pragma unroll
    for (int nt = 0; nt < 4; ++nt)
#pragma unroll
      for (int r = 0; r < 4; ++r) {
        float p = __expf(sacc[nt][r] - mnew);
        sacc[nt][r] = p;
        rs += p;
      }
    rs += __shfl_xor(rs, 16);
    rs += __shfl_xor(rs, 32);
    lrun = lrun * corr + rs;
    mrun = mnew;

    // broadcast corr from q-column layout (q=l15) to oacc row layout (q=g*4+r)
    float corrR[4];
#pragma unroll
    for (int r = 0; r < 4; ++r) corrR[r] = __shfl(corr, g * 4 + r);
#pragma unroll
    for (int dt = 0; dt < 4; ++dt)
#pragma unroll
      for (int r = 0; r < 4; ++r) oacc[dt][r] *= corrR[r];

    // pack P as A-operands: chunk ch covers keys [ch*32, ch*32+32)
    // A elem e<4 = P[kt=2ch][g*4+e], e>=4 = P[kt=2ch+1][g*4+e-4]
    short8 pa[2];
#pragma unroll
    for (int ch = 0; ch < 2; ++ch)
#pragma unroll
      for (int r = 0; r < 4; ++r) {
        pa[ch][r] = (short)f2bf_fast(sacc[2 * ch][r]);
        pa[ch][r + 4] = (short)f2bf_fast(sacc[2 * ch + 1][r]);
      }

    // O[q][d] += P V: B elem matches A's key per slot — two b64 V^T reads
#pragma unroll
    for (int ch = 0; ch < 2; ++ch)
#pragma unroll
      for (int dt = 0; dt < 4; ++dt) {
        int row = dt * 16 + l15;
        int linA = row * 128 + ch * 64 + g * 8;       // keys 2ch*16 + g*4..+3
        int linB = linA + 32;                          // keys (2ch+1)*16 + g*4..+3
        short4v va = *(const short4v*)((const char*)Vs + (linA ^ ((row & 7) << 4)));
        short4v vb = *(const short4v*)((const char*)Vs + (linB ^ ((row & 7) << 4)));
        short8 vf = __builtin_shufflevector(va, vb, 0, 1, 2, 3, 4, 5, 6, 7);
        oacc[dt] = __builtin_amdgcn_mfma_f32_16x16x32_bf16(pa[ch], vf, oacc[dt], 0, 0, 0);
      }
  }

  // epilogue: oacc D[q_loc = g*4+r][d = dt*16+l15]
  float linv = 1.0f / lrun;
  float linvR[4];
#pragma unroll
  for (int r = 0; r < 4; ++r) linvR[r] = __shfl(linv, g * 4 + r);
#pragma unroll
  for (int r = 0; r < 4; ++r) {
    int nseq = q0 + w * 16 + g * 4 + r;
#pragma unroll
    for (int dt = 0; dt < 4; ++dt) {
      int d = dt * 16 + l15;
      AO[(size_t)(b * 1024 + nseq) * 1024 + h * 64 + d] = f2bf(oacc[dt][r] * linvR[r]);
    }
  }
}

extern "C" void kernel_launch(void* const* d_in, const int* in_sizes, int n_in,
                              void* d_out, int out_size, void* d_ws, size_t ws_size,
                              hipStream_t stream) {
  const float* x = (const float*)d_in[0];
  const float* qkv_w = (const float*)d_in[1];
  const float* qkv_b = (const float*)d_in[2];
  const float* proj_w = (const float*)d_in[3];
  const float* proj_b = (const float*)d_in[4];
  float* out = (float*)d_out;

  char* ws = (char*)d_ws;
  size_t off = 0;
  auto alloc = [&](size_t bytes) -> void* {
    void* p = ws + off;
    off += (bytes + 255) & ~(size_t)255;
    return p;
  };
  ushort* xb = (ushort*)alloc(4096ull * 1024 * 2);
  ushort* wqkvb = (ushort*)alloc(3072ull * 1024 * 2);
  ushort* wprojb = (ushort*)alloc(1024ull * 1024 * 2);
  ushort* qkv = (ushort*)alloc(4096ull * 3072 * 2);
  ushort* Qb = (ushort*)alloc(64ull * 1024 * 64 * 2);
  ushort* Kb = (ushort*)alloc(64ull * 1024 * 64 * 2);
  ushort* Vt = (ushort*)alloc(64ull * 1024 * 64 * 2);
  ushort* AO = (ushort*)alloc(4096ull * 1024 * 2);
  float2* tab = (float2*)alloc(1024ull * 32 * sizeof(float2));

  cast_f32_bf16<<<2048, 256, 0, stream>>>(x, xb, 4096 * 1024);
  cast_f32_bf16<<<1536, 256, 0, stream>>>(qkv_w, wqkvb, 3072 * 1024);
  cast_f32_bf16<<<512, 256, 0, stream>>>(proj_w, wprojb, 1024 * 1024);
  rope_table<<<128, 256, 0, stream>>>(tab);

  dim3 g1(24, 32);
  gemm_bt<3072, true><<<g1, 256, 0, stream>>>(xb, wqkvb, qkv_b, qkv, 1024);

  rope_qk<<<8192, 256, 0, stream>>>(qkv, tab, Qb, Kb);
  dim3 gv(16, 64);
  v_trans<<<gv, 256, 0, stream>>>(qkv, Vt);

  attn<<<1024, 256, 0, stream>>>(Qb, Kb, Vt, AO);

  dim3 g2(8, 32);
  gemm_bt<1024, false><<<g2, 256, 0, stream>>>(AO, wprojb, proj_b, out, 1024);
}

// Round 3
// 118.697 us; speedup vs baseline: 1.2324x; 1.0404x over previous
//
#include <hip/hip_runtime.h>
#include <hip/hip_bf16.h>
#include <stdint.h>

#define DEVI __device__ __forceinline__

typedef __attribute__((ext_vector_type(8))) short short8;
typedef __attribute__((ext_vector_type(4))) short short4v;
typedef __attribute__((ext_vector_type(4))) float floatx4;

DEVI ushort f2bf(float f) {
  union { float f; uint32_t u; } v; v.f = f;
  uint32_t u = v.u;
  uint32_t r = (u + 0x7FFFu + ((u >> 16) & 1u)) >> 16;
  return (ushort)r;
}
DEVI ushort f2bf_fast(float f) {
  union { float f; uint32_t u; } v; v.f = f;
  return (ushort)((v.u + 0x8000u) >> 16);
}
DEVI float bf2f(ushort h) {
  union { uint32_t u; float f; } v; v.u = ((uint32_t)h) << 16;
  return v.f;
}
DEVI void gld_lds16(const void* g, void* l) {
  __builtin_amdgcn_global_load_lds(
      (const __attribute__((address_space(1))) unsigned int*)g,
      (__attribute__((address_space(3))) unsigned int*)l, 16, 0, 0);
}

// ---------------- cast fp32 -> bf16 ----------------
__global__ __launch_bounds__(256, 4) void cast_f32_bf16(
    const float* __restrict__ in, ushort* __restrict__ out, int n) {
  int i = (blockIdx.x * 256 + threadIdx.x) * 4;
  int stride = gridDim.x * 256 * 4;
  for (; i < n; i += stride) {
    float4 v = *(const float4*)(in + i);
    ushort4 o;
    o.x = f2bf(v.x); o.y = f2bf(v.y); o.z = f2bf(v.z); o.w = f2bf(v.w);
    *(ushort4*)(out + i) = o;
  }
}

// ---------------- RoPE cos/sin table ----------------
__global__ __launch_bounds__(256, 4) void rope_table(float2* __restrict__ tab) {
  int id = blockIdx.x * 256 + threadIdx.x;  // 1024*32
  int j = id & 31, n = id >> 5;
  float inv = powf(10000.0f, -(float)(2 * j) / 64.0f);
  float fr = (float)n * inv;
  tab[id] = make_float2(cosf(fr), sinf(fr));
}

// ---------------- GEMM: C[M][N] = A[M][K] * B[N][K]^T + bias ----------------
template <int NSTRIDE, bool OUTBF16>
__global__ __launch_bounds__(256, 2) void gemm_bt(
    const ushort* __restrict__ A, const ushort* __restrict__ Bm,
    const float* __restrict__ bias, void* __restrict__ Cout, int K) {
  __shared__ ushort As[128 * 32];
  __shared__ ushort Bs[128 * 32];
  const int tid = threadIdx.x;
  const int w = tid >> 6, lane = tid & 63;
  const int m0 = blockIdx.y * 128, n0 = blockIdx.x * 128;
  const int wm = (w >> 1) * 64, wn = (w & 1) * 64;
  const int lrow = lane & 15, lk = (lane >> 4) * 8;

  const ushort* agp = A + (size_t)(m0 + w * 32 + (lane >> 2)) * K + (lane & 3) * 8;
  const ushort* bgp = Bm + (size_t)(n0 + w * 32 + (lane >> 2)) * K + (lane & 3) * 8;
  ushort* asl = As + (w * 32) * 32 + lane * 8;
  ushort* bsl = Bs + (w * 32) * 32 + lane * 8;

  floatx4 acc[4][4] = {};

  for (int k0 = 0; k0 < K; k0 += 32) {
    __syncthreads();
    gld_lds16(agp, asl);
    gld_lds16(agp + 16 * K, asl + 16 * 32);
    gld_lds16(bgp, bsl);
    gld_lds16(bgp + 16 * K, bsl + 16 * 32);
    agp += 32; bgp += 32;
    __syncthreads();
    short8 af[4], bf[4];
#pragma unroll
    for (int t = 0; t < 4; ++t) {
      af[t] = *(const short8*)(As + (wm + t * 16 + lrow) * 32 + lk);
      bf[t] = *(const short8*)(Bs + (wn + t * 16 + lrow) * 32 + lk);
    }
#pragma unroll
    for (int i = 0; i < 4; ++i)
#pragma unroll
      for (int j = 0; j < 4; ++j)
        acc[i][j] = __builtin_amdgcn_mfma_f32_16x16x32_bf16(af[i], bf[j], acc[i][j], 0, 0, 0);
  }

#pragma unroll
  for (int i = 0; i < 4; ++i) {
    int mrow = m0 + wm + i * 16 + (lane >> 4) * 4;
#pragma unroll
    for (int j = 0; j < 4; ++j) {
      int ncol = n0 + wn + j * 16 + (lane & 15);
      float bv = bias[ncol];
#pragma unroll
      for (int r = 0; r < 4; ++r) {
        float v = acc[i][j][r] + bv;
        if (OUTBF16)
          ((ushort*)Cout)[(size_t)(mrow + r) * NSTRIDE + ncol] = f2bf(v);
        else
          ((float*)Cout)[(size_t)(mrow + r) * NSTRIDE + ncol] = v;
      }
    }
  }
}

// ---------------- RoPE + scatter q,k -> (b,h,n,d) ----------------
// log2(e) folded into q's scale so attn softmax can use raw exp2.
__global__ __launch_bounds__(256, 4) void rope_qk(
    const ushort* __restrict__ qkv, const float2* __restrict__ tab,
    ushort* __restrict__ Q, ushort* __restrict__ Kb) {
  int id = blockIdx.x * 256 + threadIdx.x;  // 4096*16*32
  int j = id & 31;
  int h = (id >> 5) & 15;
  int m = id >> 9;  // 0..4095
  int b = m >> 10, n = m & 1023;
  const ushort* row = qkv + (size_t)m * 3072;
  int idx = h * 64 + 2 * j;
  uint32_t qp = *(const uint32_t*)(row + idx);
  uint32_t kp = *(const uint32_t*)(row + 1024 + idx);
  float2 cs = tab[n * 32 + j];
  float q0 = bf2f((ushort)qp), q1 = bf2f((ushort)(qp >> 16));
  float k0 = bf2f((ushort)kp), k1 = bf2f((ushort)(kp >> 16));
  const float sc = (1.0f / 64.0f) * 1.44269504088896f;  // scale^2 * log2(e)
  float q0r = (q0 * cs.x - q1 * cs.y) * sc;
  float q1r = (q1 * cs.x + q0 * cs.y) * sc;
  float k0r = k0 * cs.x - k1 * cs.y;
  float k1r = k1 * cs.x + k0 * cs.y;
  size_t o = ((size_t)(b * 16 + h) * 1024 + n) * 64 + 2 * j;
  *(uint32_t*)(Q + o) = (uint32_t)f2bf(q0r) | ((uint32_t)f2bf(q1r) << 16);
  *(uint32_t*)(Kb + o) = (uint32_t)f2bf(k0r) | ((uint32_t)f2bf(k1r) << 16);
}

// ---------------- V transpose -> Vt (b,h,d,n) ----------------
__global__ __launch_bounds__(256, 4) void v_trans(
    const ushort* __restrict__ qkv, ushort* __restrict__ Vt) {
  __shared__ ushort t[64][72];
  int bh = blockIdx.y, ntile = blockIdx.x;
  int b = bh >> 4, h = bh & 15;
  int n0 = ntile * 64;
  int tid = threadIdx.x;
  int r = tid >> 2, cc = (tid & 3) * 16;
  const ushort* src = qkv + (size_t)(b * 1024 + n0 + r) * 3072 + 2048 + h * 64 + cc;
  *(short8*)(&t[r][cc]) = *(const short8*)(src);
  *(short8*)(&t[r][cc + 8]) = *(const short8*)(src + 8);
  __syncthreads();
  int d = tid >> 2;
  ushort outv[16];
#pragma unroll
  for (int i = 0; i < 16; ++i) outv[i] = t[cc + i][d];
  ushort* dst = Vt + (size_t)bh * 65536 + (size_t)d * 1024 + n0 + cc;
  *(short8*)(dst) = *(const short8*)(outv);
  *(short8*)(dst + 8) = *(const short8*)(outv + 8);
}

// ---------------- Flash attention v3 ----------------
// v2 + T3-minimum double-buffered pipeline (counted by full compute overlap,
// raw barrier, one drain/tile), hoisted LDS addresses, exp2 softmax,
// defer-max (T13), setprio around MFMA (T5).
__global__ __launch_bounds__(256, 4) void attn(
    const ushort* __restrict__ Q, const ushort* __restrict__ Kc,
    const ushort* __restrict__ Vt, ushort* __restrict__ AO) {
  __shared__ char lds[2][16384];  // per buf: K tile 8KB @0, V tile 8KB @8192
  char* ldsbase = &lds[0][0];
  int id = blockIdx.x;
  int bh = id & 63, qi = id >> 6;
  int b = bh >> 4, h = bh & 15;
  int q0 = qi * 64;
  int tid = threadIdx.x, w = tid >> 6, lane = tid & 63;
  int l15 = lane & 15, g = lane >> 4;
  const ushort* Qbh = Q + (size_t)bh * 65536;
  const char* Kbh = (const char*)(Kc + (size_t)bh * 65536);
  const char* Vbh = (const char*)(Vt + (size_t)bh * 65536);

  // Q fragment (B-operand of swapped QK^T)
  short8 qf[2];
#pragma unroll
  for (int ks = 0; ks < 2; ++ks)
    qf[ks] = *(const short8*)(Qbh + (size_t)(q0 + w * 16 + l15) * 64 + ks * 32 + g * 8);

  // hoisted swizzled LDS read addresses (loop-invariant)
  int kaddr[8];   // [ks][nt]
#pragma unroll
  for (int ks = 0; ks < 2; ++ks)
#pragma unroll
    for (int nt = 0; nt < 4; ++nt) {
      int row = nt * 16 + l15;
      kaddr[ks * 4 + nt] = (row * 128 + ks * 64 + g * 16) ^ ((row & 7) << 4);
    }
  int vaddr[16];  // [ch][dt][half]
#pragma unroll
  for (int ch = 0; ch < 2; ++ch)
#pragma unroll
    for (int dt = 0; dt < 4; ++dt)
#pragma unroll
      for (int hf = 0; hf < 2; ++hf) {
        int row = dt * 16 + l15;
        vaddr[(ch * 4 + dt) * 2 + hf] =
            8192 + ((row * 128 + ch * 64 + hf * 32 + g * 8) ^ ((row & 7) << 4));
      }

  // staging pointers (source pre-swizzled; dest linear)
  const int d0 = w * 2048 + lane * 16;
  const int d1 = d0 + 1024;
  const int r0 = d0 >> 7, r1 = d1 >> 7;
  const int s0 = d0 ^ ((r0 & 7) << 4), s1 = d1 ^ ((r1 & 7) << 4);
  const char* pK0 = Kbh + s0;
  const char* pK1 = Kbh + s1;
  const char* pV0 = Vbh + r0 * 2048 + (s0 & 127);
  const char* pV1 = Vbh + r1 * 2048 + (s1 & 127);

  auto STAGE = [&](const int B) {
    gld_lds16(pK0, ldsbase + B + d0);
    gld_lds16(pK1, ldsbase + B + d1);
    gld_lds16(pV0, ldsbase + B + 8192 + d0);
    gld_lds16(pV1, ldsbase + B + 8192 + d1);
    pK0 += 8192; pK1 += 8192; pV0 += 128; pV1 += 128;
  };

  floatx4 oacc[4] = {};
  float mrun = -1e30f, lrun = 0.f;

  auto TILE = [&](const int B) {
    // S^T = mfma(K, Q): D[key_loc][q], key_loc = nt*16+g*4+r, q = l15
    floatx4 sacc[4] = {};
    __builtin_amdgcn_s_setprio(1);
#pragma unroll
    for (int ks = 0; ks < 2; ++ks) {
      short8 kf[4];
#pragma unroll
      for (int nt = 0; nt < 4; ++nt)
        kf[nt] = *(const short8*)(ldsbase + B + kaddr[ks * 4 + nt]);
#pragma unroll
      for (int nt = 0; nt < 4; ++nt)
        sacc[nt] = __builtin_amdgcn_mfma_f32_16x16x32_bf16(kf[nt], qf[ks], sacc[nt], 0, 0, 0);
    }
    __builtin_amdgcn_s_setprio(0);

    // online softmax in exp2 domain; defer-max: skip rescale when max grew < 4
    float mx = sacc[0][0];
#pragma unroll
    for (int nt = 0; nt < 4; ++nt)
#pragma unroll
      for (int r = 0; r < 4; ++r) mx = fmaxf(mx, sacc[nt][r]);
    mx = fmaxf(mx, __shfl_xor(mx, 16));
    mx = fmaxf(mx, __shfl_xor(mx, 32));
    if (__any(mx > mrun + 4.0f)) {
      float mnew = fmaxf(mrun, mx);
      float corr = __builtin_amdgcn_exp2f(mrun - mnew);
      lrun *= corr;
      float corrR[4];
#pragma unroll
      for (int r = 0; r < 4; ++r) corrR[r] = __shfl(corr, g * 4 + r);
#pragma unroll
      for (int dt = 0; dt < 4; ++dt)
#pragma unroll
        for (int r = 0; r < 4; ++r) oacc[dt][r] *= corrR[r];
      mrun = mnew;
    }
    float rs = 0.f;
#pragma unroll
    for (int nt = 0; nt < 4; ++nt)
#pragma unroll
      for (int r = 0; r < 4; ++r) {
        float p = __builtin_amdgcn_exp2f(sacc[nt][r] - mrun);
        sacc[nt][r] = p;
        rs += p;
      }
    rs += __shfl_xor(rs, 16);
    rs += __shfl_xor(rs, 32);
    lrun += rs;

    // pack P (keys stay lane-local; slot sigma(g,e<4)=ch*32+g*4+e, e>=4: +16)
    short8 pa[2];
#pragma unroll
    for (int ch = 0; ch < 2; ++ch)
#pragma unroll
      for (int r = 0; r < 4; ++r) {
        pa[ch][r] = (short)f2bf_fast(sacc[2 * ch][r]);
        pa[ch][r + 4] = (short)f2bf_fast(sacc[2 * ch + 1][r]);
      }

    // O += P V
    __builtin_amdgcn_s_setprio(1);
#pragma unroll
    for (int ch = 0; ch < 2; ++ch)
#pragma unroll
      for (int dt = 0; dt < 4; ++dt) {
        short4v va = *(const short4v*)(ldsbase + B + vaddr[(ch * 4 + dt) * 2]);
        short4v vb = *(const short4v*)(ldsbase + B + vaddr[(ch * 4 + dt) * 2 + 1]);
        short8 vf = __builtin_shufflevector(va, vb, 0, 1, 2, 3, 4, 5, 6, 7);
        oacc[dt] = __builtin_amdgcn_mfma_f32_16x16x32_bf16(pa[ch], vf, oacc[dt], 0, 0, 0);
      }
    __builtin_amdgcn_s_setprio(0);
  };

  // prologue
  STAGE(0);
  asm volatile("s_waitcnt vmcnt(0)" ::: "memory");
  __builtin_amdgcn_s_barrier();
  __builtin_amdgcn_sched_barrier(0);

  for (int kt = 0; kt < 16; kt += 2) {
    STAGE(16384);                    // stage kt+1 into buf1
    __builtin_amdgcn_sched_barrier(0);
    TILE(0);                         // compute kt on buf0
    asm volatile("s_waitcnt vmcnt(0)" ::: "memory");
    __builtin_amdgcn_s_barrier();
    __builtin_amdgcn_sched_barrier(0);

    if (kt + 2 < 16) STAGE(0);       // stage kt+2 into buf0
    __builtin_amdgcn_sched_barrier(0);
    TILE(16384);                     // compute kt+1 on buf1
    asm volatile("s_waitcnt vmcnt(0)" ::: "memory");
    __builtin_amdgcn_s_barrier();
    __builtin_amdgcn_sched_barrier(0);
  }

  // epilogue: oacc D[q_loc = g*4+r][d = dt*16+l15]
  float linv = 1.0f / lrun;
  float linvR[4];
#pragma unroll
  for (int r = 0; r < 4; ++r) linvR[r] = __shfl(linv, g * 4 + r);
#pragma unroll
  for (int r = 0; r < 4; ++r) {
    int nseq = q0 + w * 16 + g * 4 + r;
#pragma unroll
    for (int dt = 0; dt < 4; ++dt) {
      int d = dt * 16 + l15;
      AO[(size_t)(b * 1024 + nseq) * 1024 + h * 64 + d] = f2bf(oacc[dt][r] * linvR[r]);
    }
  }
}

extern "C" void kernel_launch(void* const* d_in, const int* in_sizes, int n_in,
                              void* d_out, int out_size, void* d_ws, size_t ws_size,
                              hipStream_t stream) {
  const float* x = (const float*)d_in[0];
  const float* qkv_w = (const float*)d_in[1];
  const float* qkv_b = (const float*)d_in[2];
  const float* proj_w = (const float*)d_in[3];
  const float* proj_b = (const float*)d_in[4];
  float* out = (float*)d_out;

  char* ws = (char*)d_ws;
  size_t off = 0;
  auto alloc = [&](size_t bytes) -> void* {
    void* p = ws + off;
    off += (bytes + 255) & ~(size_t)255;
    return p;
  };
  ushort* xb = (ushort*)alloc(4096ull * 1024 * 2);
  ushort* wqkvb = (ushort*)alloc(3072ull * 1024 * 2);
  ushort* wprojb = (ushort*)alloc(1024ull * 1024 * 2);
  ushort* qkv = (ushort*)alloc(4096ull * 3072 * 2);
  ushort* Qb = (ushort*)alloc(64ull * 1024 * 64 * 2);
  ushort* Kb = (ushort*)alloc(64ull * 1024 * 64 * 2);
  ushort* Vt = (ushort*)alloc(64ull * 1024 * 64 * 2);
  ushort* AO = (ushort*)alloc(4096ull * 1024 * 2);
  float2* tab = (float2*)alloc(1024ull * 32 * sizeof(float2));

  cast_f32_bf16<<<2048, 256, 0, stream>>>(x, xb, 4096 * 1024);
  cast_f32_bf16<<<1536, 256, 0, stream>>>(qkv_w, wqkvb, 3072 * 1024);
  cast_f32_bf16<<<512, 256, 0, stream>>>(proj_w, wprojb, 1024 * 1024);
  rope_table<<<128, 256, 0, stream>>>(tab);

  dim3 g1(24, 32);
  gemm_bt<3072, true><<<g1, 256, 0, stream>>>(xb, wqkvb, qkv_b, qkv, 1024);

  rope_qk<<<8192, 256, 0, stream>>>(qkv, tab, Qb, Kb);
  dim3 gv(16, 64);
  v_trans<<<gv, 256, 0, stream>>>(qkv, Vt);

  attn<<<1024, 256, 0, stream>>>(Qb, Kb, Vt, AO);

  dim3 g2(8, 32);
  gemm_bt<1024, false><<<g2, 256, 0, stream>>>(AO, wprojb, proj_b, out, 1024);
}